// Round 15
// baseline (1587.722 us; speedup 1.0000x reference)
//
#include <hip/hip_runtime.h>
#include <hip/hip_bf16.h>

#define N_NODES 100000
#define IN_F    256
#define OUT_F   64
#define D_CH    4
#define N_EDGE  800000
#define EP1     (N_EDGE + 1)               // per-channel rec slots (+1 sentinel)
#define M_SEG   (D_CH * N_NODES)          // 400000 segments
#define CPW     8                          // chains per wave (R7-proven optimum)
#define GROWS   128                        // gemm rows per block (8 waves)
#define NBKT    64                         // degree buckets (clamped)

typedef __attribute__((ext_vector_type(8))) short short8;
typedef __attribute__((ext_vector_type(4))) float f32x4;

__device__ inline ushort f2bf(float f) {           // round-to-nearest-even
    union { float f; unsigned u; } v; v.f = f;
    unsigned b = v.u + 0x7FFFu + ((v.u >> 16) & 1u);
    return (ushort)(b >> 16);
}
__device__ inline float bf2f(ushort u) {
    union { unsigned u; float f; } v; v.u = ((unsigned)u) << 16;
    return v.f;
}
__device__ inline float bits2f(int b) {
    union { int i; float f; } v; v.i = b; return v.f;
}
// native paired f32->bf16 (compiler emits v_cvt_pk_bf16_f32; RNE)
__device__ inline void cvt2(float a, float b, ushort& lo, ushort& hi) {
    __hip_bfloat162 h = __float22bfloat162_rn(float2{a, b});
    union { __hip_bfloat162 h; ushort2 u; } v; v.h = h;
    lo = v.u.x; hi = v.u.y;
}

// ---------------------------------------------------------------------------
// One-time: repack W (f32) into per-lane bf16 MFMA B-fragments.
// ---------------------------------------------------------------------------
__global__ __launch_bounds__(256) void bpack_kernel(
    const float* __restrict__ W, ushort* __restrict__ Bpack)
{
    const int t = blockIdx.x * 256 + threadIdx.x;      // 0 .. 8191
    if (t >= D_CH * 8 * 4 * 64) return;
    const int l  = t & 63;
    const int nt = (t >> 6) & 3;
    const int ks = (t >> 8) & 7;
    const int i  = t >> 11;
    const int n  = nt * 16 + (l & 15);
    const int k0 = ks * 32 + (l >> 4) * 8;
    ushort v[8];
#pragma unroll
    for (int j = 0; j < 8; ++j)
        v[j] = f2bf(W[((size_t)i * IN_F + k0 + j) * OUT_F + n]);
#pragma unroll
    for (int j = 0; j < 8; ++j)
        Bpack[(size_t)t * 8 + j] = v[j];
}

// ---------------------------------------------------------------------------
// Init: head = sentinel; deg = 0; bucket counters = 0; sentinel record.
// ---------------------------------------------------------------------------
__global__ __launch_bounds__(256) void init_kernel(
    int* __restrict__ head, int4* __restrict__ rec,
    int* __restrict__ deg, int* __restrict__ bcnt)
{
    const int t = blockIdx.x * 256 + threadIdx.x;
    if (t < M_SEG) { head[t] = N_EDGE; deg[t] = 0; }
    if (t < D_CH * NBKT) bcnt[t] = 0;
    if (t < D_CH) rec[(size_t)t * EP1 + N_EDGE] = make_int4(N_EDGE, 0, 0, 0);
}

// ---------------------------------------------------------------------------
// MFMA GEMM + fused pvec epilogue. 8 waves/128 rows; B staged in LDS. (R13)
// C/D layout (HW-verified): col = lane&15, row = (lane>>4)*4 + reg.
// ---------------------------------------------------------------------------
__global__ __launch_bounds__(512) void gemm_mfma_kernel(
    const float* __restrict__ feature, const float* __restrict__ norm,
    const ushort* __restrict__ Bpack, const float* __restrict__ att_w,
    ushort* __restrict__ Wh_b, float* __restrict__ p_src, float* __restrict__ p_dst)
{
    __shared__ ushort Blds[16384];            // 32KB: one channel's 32 fragments
    const int wv   = threadIdx.x >> 6;        // 0..7
    const int lane = threadIdx.x & 63;
    const int kg   = lane >> 4;
    const int cl   = lane & 15;
    const int r0   = blockIdx.x * GROWS + wv * 16;

    const int rowm   = r0 + cl;
    const int rclamp = (rowm < N_NODES) ? rowm : (N_NODES - 1);
    const float* __restrict__ arow = feature + (size_t)rclamp * IN_F + kg * 8;
    short8 afrag[8];
#pragma unroll
    for (int ks = 0; ks < 8; ++ks) {
        const f32x4 x = *(const f32x4*)(arow + ks * 32);
        const f32x4 y = *(const f32x4*)(arow + ks * 32 + 4);
        ushort u[8];
        cvt2(x[0], x[1], u[0], u[1]);
        cvt2(x[2], x[3], u[2], u[3]);
        cvt2(y[0], y[1], u[4], u[5]);
        cvt2(y[2], y[3], u[6], u[7]);
        short8 a;
#pragma unroll
        for (int j = 0; j < 8; ++j) a[j] = (short)u[j];
        afrag[ks] = a;
    }

    float pa[4], pb[4];
#pragma unroll
    for (int nt = 0; nt < 4; ++nt) {
        pa[nt] = att_w[nt * 16 + cl];
        pb[nt] = att_w[OUT_F + nt * 16 + cl];
    }
    float nm[4];
    bool  rvld[4];
#pragma unroll
    for (int r = 0; r < 4; ++r) {
        const int rr = r0 + kg * 4 + r;
        rvld[r] = rr < N_NODES;
        nm[r] = rvld[r] ? norm[rr] : 0.f;
    }

    for (int i = 0; i < D_CH; ++i) {
        __syncthreads();
        {
            const uint4* __restrict__ s4 = (const uint4*)(Bpack + (size_t)i * 16384);
            uint4* d4 = (uint4*)Blds;
#pragma unroll
            for (int t = 0; t < 4; ++t)
                d4[threadIdx.x + t * 512] = s4[threadIdx.x + t * 512];
        }
        __syncthreads();

        f32x4 acc[4];
#pragma unroll
        for (int nt = 0; nt < 4; ++nt) acc[nt] = (f32x4){0.f, 0.f, 0.f, 0.f};

#pragma unroll
        for (int ks = 0; ks < 8; ++ks) {
#pragma unroll
            for (int nt = 0; nt < 4; ++nt) {
                const short8 bf =
                    *(const short8*)(Blds + (((ks * 4 + nt) << 6) + lane) * 8);
                acc[nt] = __builtin_amdgcn_mfma_f32_16x16x32_bf16(
                    afrag[ks], bf, acc[nt], 0, 0, 0);
            }
        }

        float vv[4][4];
        float ps[4] = {0.f, 0.f, 0.f, 0.f}, pd[4] = {0.f, 0.f, 0.f, 0.f};
#pragma unroll
        for (int nt = 0; nt < 4; ++nt) {
#pragma unroll
            for (int r = 0; r < 4; ++r) {
                const float v = acc[nt][r] * nm[r];
                vv[nt][r] = v;
                ps[r] += v * pa[nt];
                pd[r] += v * pb[nt];
            }
        }
#pragma unroll
        for (int r = 0; r < 4; ++r) {
            const int rr = r0 + kg * 4 + r;
            if (!rvld[r]) continue;
            ushort u0, u1, u2, u3;
            cvt2(vv[0][r], vv[1][r], u0, u1);
            cvt2(vv[2][r], vv[3][r], u2, u3);
            ushort* wrow = Wh_b + ((size_t)i * N_NODES + rr) * OUT_F + cl;
            wrow[0]  = u0;
            wrow[16] = u1;
            wrow[32] = u2;
            wrow[48] = u3;
        }
#pragma unroll
        for (int r = 0; r < 4; ++r) {
            float s1 = ps[r], s2 = pd[r];
#pragma unroll
            for (int off = 1; off < 16; off <<= 1) {
                s1 += __shfl_xor(s1, off, 64);
                s2 += __shfl_xor(s2, off, 64);
            }
            if (cl == 0 && rvld[r]) {
                const int rr = r0 + kg * 4 + r;
                p_src[i * N_NODES + rr] = s1;
                p_dst[i * N_NODES + rr] = s2;
            }
        }
    }
}

// ---------------------------------------------------------------------------
// Linked-list build (R11) + fused degree histogram.
// ---------------------------------------------------------------------------
__global__ __launch_bounds__(256) void build_kernel(
    const int* __restrict__ src, const int* __restrict__ dst,
    const float* __restrict__ p_src, const float* __restrict__ p_dst,
    int* __restrict__ head, int4* __restrict__ rec, int* __restrict__ deg)
{
    const int e = blockIdx.x * 256 + threadIdx.x;
    const int i = blockIdx.y;
    const int d = dst[(size_t)i * N_EDGE + e];
    const int s = src[(size_t)i * N_EDGE + e];
    float x = p_src[i * N_NODES + s] + p_dst[i * N_NODES + d];
    x = (x > 0.f) ? x : 0.2f * x;
    const float w = __expf(x);   // max-free softmax: logits O(4), no overflow
    union { float f; int i; } wb; wb.f = w;
    const int old = atomicExch(&head[i * N_NODES + d], e);
    atomicAdd(&deg[i * N_NODES + d], 1);
    rec[(size_t)i * EP1 + e] = make_int4(old, s << 7, wb.i, 0);
}

// ---------------------------------------------------------------------------
// Degree-balance machinery: bucket-count -> per-channel scan -> perm scatter.
// (R14 crash fix: grid over-covers N_NODES -> bounds guards REQUIRED.)
// ---------------------------------------------------------------------------
__global__ __launch_bounds__(256) void bcnt_kernel(
    const int* __restrict__ deg, int* __restrict__ bcnt)
{
    const int n = blockIdx.x * 256 + threadIdx.x;
    if (n >= N_NODES) return;                 // R14 bug: missing guard
    const int i = blockIdx.y;
    const int b = min(deg[i * N_NODES + n], NBKT - 1);
    atomicAdd(&bcnt[i * NBKT + b], 1);
}

__global__ __launch_bounds__(256) void bscan_kernel(
    const int* __restrict__ bcnt, int* __restrict__ bcursor)
{
    __shared__ int lds[D_CH * NBKT];
    const int t = threadIdx.x;               // 256 = 4 channels x 64 buckets
    const int b = t & (NBKT - 1);
    const int i = t >> 6;
    const int c = bcnt[t];
    lds[t] = c;
    __syncthreads();
    for (int off = 1; off < NBKT; off <<= 1) {
        int v = 0;
        if (b >= off) v = lds[t - off];
        __syncthreads();
        if (b >= off) lds[t] += v;
        __syncthreads();
    }
    bcursor[t] = i * N_NODES + lds[t] - c;   // exclusive base within channel
}

__global__ __launch_bounds__(256) void perm_kernel(
    const int* __restrict__ deg, int* __restrict__ bcursor,
    int* __restrict__ perm)
{
    const int n = blockIdx.x * 256 + threadIdx.x;
    if (n >= N_NODES) return;                 // R14 bug: missing guard
    const int i = blockIdx.y;
    const int b = min(deg[i * N_NODES + n], NBKT - 1);
    const int pos = atomicAdd(&bcursor[i * NBKT + b], 1);
    perm[pos] = n;
}

// ---------------------------------------------------------------------------
// Aggregate via sentinel-terminated lists over DEGREE-BALANCED node groups:
// chain c handles node perm[i*N + n0 + c]; waves (mostly) take equal-degree
// nodes -> iterations ~= degree, no slack. Termination sums PRE-ingest next
// pointers (R10 lesson); handles unequal degrees at bucket edges correctly.
// ---------------------------------------------------------------------------
__global__ __launch_bounds__(256) void agg_ll_kernel(
    const int* __restrict__ head, const int4* __restrict__ rec,
    const int* __restrict__ perm, const ushort* __restrict__ Wh_b,
    const float* __restrict__ norm, float* __restrict__ out)
{
    const int wv    = threadIdx.x >> 6;
    const int lane  = threadIdx.x & 63;
    const int lane2 = lane * 2;
    const int i     = blockIdx.y;
    const int n0    = (blockIdx.x * 4 + wv) * CPW;  // 8 perm slots

    const int4* __restrict__ recb = rec + (size_t)i * EP1;
    const char* __restrict__ whb0 =
        (const char*)(Wh_b + (size_t)i * N_NODES * OUT_F);

    // ---- prologue: resolve nodes, ingest head edge of each chain ----
    int   nd[CPW], sb[CPW], en[CPW];
    float w[CPW], acc[CPW], z[CPW];
#pragma unroll
    for (int c = 0; c < CPW; ++c) {
        nd[c] = perm[i * N_NODES + n0 + c];
        const int4 r = recb[head[i * N_NODES + nd[c]]];
        sb[c]  = r.y;
        w[c]   = bits2f(r.z);
        en[c]  = r.x;
        acc[c] = 0.f;
        z[c]   = 0.f;
    }

    for (;;) {
        int sum = 0;
#pragma unroll
        for (int c = 0; c < CPW; ++c) {
            // two independent loads -> single wait covers both
            const float wh = bf2f(*(const ushort*)(whb0 + (sb[c] + lane2)));
            const int4  r  = recb[en[c]];

            acc[c] += w[c] * wh;     // w==0 on sentinel: harmless
            z[c]   += w[c];

            sum  += en[c];           // PRE-ingest: current's successor pointer

            sb[c] = r.y;
            w[c]  = bits2f(r.z);
            en[c] = r.x;
        }
        if (sum == CPW * N_EDGE) break;
    }

#pragma unroll
    for (int c = 0; c < CPW; ++c) {
        const int n = nd[c];
        float v = (z[c] > 0.f) ? (acc[c] / z[c]) * norm[n] : 0.f;
        out[(size_t)n * (D_CH * OUT_F) + i * OUT_F + lane] = (v > 0.f) ? v : 0.f;
    }
}

// ---------------------------------------------------------------------------
extern "C" void kernel_launch(void* const* d_in, const int* in_sizes, int n_in,
                              void* d_out, int out_size, void* d_ws, size_t ws_size,
                              hipStream_t stream)
{
    const float* feature = (const float*)d_in[0];
    const float* norm    = (const float*)d_in[1];
    const float* W       = (const float*)d_in[2];
    const float* att_w   = (const float*)d_in[3];
    const int*   src     = (const int*)d_in[4];
    const int*   dst     = (const int*)d_in[5];
    float* out = (float*)d_out;

    // Workspace layout (~110.6 MB):
    // Wh_b[51.2MB] | p_src | p_dst | head | rec[51.2MB+16B] | Bpack |
    // deg[1.6MB] | perm[1.6MB] | bcnt[256] | bcursor[256]
    ushort* Wh_b  = (ushort*)d_ws;
    float*  p_src = (float*)(Wh_b + (size_t)M_SEG * OUT_F);
    float*  p_dst = p_src + M_SEG;
    int*    head  = (int*)(p_dst + M_SEG);
    int4*   rec   = (int4*)(head + M_SEG);
    ushort* Bpack = (ushort*)(rec + (size_t)D_CH * EP1);
    int*    deg   = (int*)(Bpack + 65536);
    int*    perm  = deg + M_SEG;
    int*    bcnt  = perm + M_SEG;
    int*    bcursor = bcnt + D_CH * NBKT;

    bpack_kernel<<<dim3(32), 256, 0, stream>>>(W, Bpack);
    init_kernel<<<dim3((M_SEG + 255) / 256), 256, 0, stream>>>(head, rec, deg, bcnt);
    gemm_mfma_kernel<<<dim3((N_NODES + GROWS - 1) / GROWS), 512, 0, stream>>>(
        feature, norm, Bpack, att_w, Wh_b, p_src, p_dst);
    build_kernel<<<dim3(N_EDGE / 256, D_CH), 256, 0, stream>>>(
        src, dst, p_src, p_dst, head, rec, deg);
    bcnt_kernel<<<dim3((N_NODES + 255) / 256, D_CH), 256, 0, stream>>>(deg, bcnt);
    bscan_kernel<<<dim3(1), 256, 0, stream>>>(bcnt, bcursor);
    perm_kernel<<<dim3((N_NODES + 255) / 256, D_CH), 256, 0, stream>>>(
        deg, bcursor, perm);
    agg_ll_kernel<<<dim3(N_NODES / (4 * CPW), D_CH), 256, 0, stream>>>(
        head, rec, perm, Wh_b, norm, out);
}

// Round 16
// 476.669 us; speedup vs baseline: 3.3309x; 3.3309x over previous
//
#include <hip/hip_runtime.h>
#include <hip/hip_bf16.h>

#define N_NODES 100000
#define IN_F    256
#define OUT_F   64
#define D_CH    4
#define N_EDGE  800000
#define EP1     (N_EDGE + 1)               // per-channel rec slots (+1 sentinel)
#define M_SEG   (D_CH * N_NODES)          // 400000 segments
#define CPW     8                          // chains per wave (R7-proven optimum)
#define GROWS   128                        // gemm rows per block (8 waves)
#define NBKT    64                         // degree buckets (clamped)
#define NBLK    ((N_NODES + 255) / 256)    // 391 node-blocks

typedef __attribute__((ext_vector_type(8))) short short8;
typedef __attribute__((ext_vector_type(4))) float f32x4;

__device__ inline ushort f2bf(float f) {           // round-to-nearest-even
    union { float f; unsigned u; } v; v.f = f;
    unsigned b = v.u + 0x7FFFu + ((v.u >> 16) & 1u);
    return (ushort)(b >> 16);
}
__device__ inline float bf2f(ushort u) {
    union { unsigned u; float f; } v; v.u = ((unsigned)u) << 16;
    return v.f;
}
__device__ inline float bits2f(int b) {
    union { int i; float f; } v; v.i = b; return v.f;
}
// native paired f32->bf16 (compiler emits v_cvt_pk_bf16_f32; RNE)
__device__ inline void cvt2(float a, float b, ushort& lo, ushort& hi) {
    __hip_bfloat162 h = __float22bfloat162_rn(float2{a, b});
    union { __hip_bfloat162 h; ushort2 u; } v; v.h = h;
    lo = v.u.x; hi = v.u.y;
}

// ---------------------------------------------------------------------------
// One-time: repack W (f32) into per-lane bf16 MFMA B-fragments.
// ---------------------------------------------------------------------------
__global__ __launch_bounds__(256) void bpack_kernel(
    const float* __restrict__ W, ushort* __restrict__ Bpack)
{
    const int t = blockIdx.x * 256 + threadIdx.x;      // 0 .. 8191
    if (t >= D_CH * 8 * 4 * 64) return;
    const int l  = t & 63;
    const int nt = (t >> 6) & 3;
    const int ks = (t >> 8) & 7;
    const int i  = t >> 11;
    const int n  = nt * 16 + (l & 15);
    const int k0 = ks * 32 + (l >> 4) * 8;
    ushort v[8];
#pragma unroll
    for (int j = 0; j < 8; ++j)
        v[j] = f2bf(W[((size_t)i * IN_F + k0 + j) * OUT_F + n]);
#pragma unroll
    for (int j = 0; j < 8; ++j)
        Bpack[(size_t)t * 8 + j] = v[j];
}

// ---------------------------------------------------------------------------
// Init: head = sentinel; deg = 0; sentinel record.
// ---------------------------------------------------------------------------
__global__ __launch_bounds__(256) void init_kernel(
    int* __restrict__ head, int4* __restrict__ rec, int* __restrict__ deg)
{
    const int t = blockIdx.x * 256 + threadIdx.x;
    if (t < M_SEG) { head[t] = N_EDGE; deg[t] = 0; }
    if (t < D_CH) rec[(size_t)t * EP1 + N_EDGE] = make_int4(N_EDGE, 0, 0, 0);
}

// ---------------------------------------------------------------------------
// MFMA GEMM + fused pvec epilogue. 8 waves/128 rows; B staged in LDS. (R13)
// C/D layout (HW-verified): col = lane&15, row = (lane>>4)*4 + reg.
// ---------------------------------------------------------------------------
__global__ __launch_bounds__(512) void gemm_mfma_kernel(
    const float* __restrict__ feature, const float* __restrict__ norm,
    const ushort* __restrict__ Bpack, const float* __restrict__ att_w,
    ushort* __restrict__ Wh_b, float* __restrict__ p_src, float* __restrict__ p_dst)
{
    __shared__ ushort Blds[16384];            // 32KB: one channel's 32 fragments
    const int wv   = threadIdx.x >> 6;        // 0..7
    const int lane = threadIdx.x & 63;
    const int kg   = lane >> 4;
    const int cl   = lane & 15;
    const int r0   = blockIdx.x * GROWS + wv * 16;

    const int rowm   = r0 + cl;
    const int rclamp = (rowm < N_NODES) ? rowm : (N_NODES - 1);
    const float* __restrict__ arow = feature + (size_t)rclamp * IN_F + kg * 8;
    short8 afrag[8];
#pragma unroll
    for (int ks = 0; ks < 8; ++ks) {
        const f32x4 x = *(const f32x4*)(arow + ks * 32);
        const f32x4 y = *(const f32x4*)(arow + ks * 32 + 4);
        ushort u[8];
        cvt2(x[0], x[1], u[0], u[1]);
        cvt2(x[2], x[3], u[2], u[3]);
        cvt2(y[0], y[1], u[4], u[5]);
        cvt2(y[2], y[3], u[6], u[7]);
        short8 a;
#pragma unroll
        for (int j = 0; j < 8; ++j) a[j] = (short)u[j];
        afrag[ks] = a;
    }

    float pa[4], pb[4];
#pragma unroll
    for (int nt = 0; nt < 4; ++nt) {
        pa[nt] = att_w[nt * 16 + cl];
        pb[nt] = att_w[OUT_F + nt * 16 + cl];
    }
    float nm[4];
    bool  rvld[4];
#pragma unroll
    for (int r = 0; r < 4; ++r) {
        const int rr = r0 + kg * 4 + r;
        rvld[r] = rr < N_NODES;
        nm[r] = rvld[r] ? norm[rr] : 0.f;
    }

    for (int i = 0; i < D_CH; ++i) {
        __syncthreads();
        {
            const uint4* __restrict__ s4 = (const uint4*)(Bpack + (size_t)i * 16384);
            uint4* d4 = (uint4*)Blds;
#pragma unroll
            for (int t = 0; t < 4; ++t)
                d4[threadIdx.x + t * 512] = s4[threadIdx.x + t * 512];
        }
        __syncthreads();

        f32x4 acc[4];
#pragma unroll
        for (int nt = 0; nt < 4; ++nt) acc[nt] = (f32x4){0.f, 0.f, 0.f, 0.f};

#pragma unroll
        for (int ks = 0; ks < 8; ++ks) {
#pragma unroll
            for (int nt = 0; nt < 4; ++nt) {
                const short8 bf =
                    *(const short8*)(Blds + (((ks * 4 + nt) << 6) + lane) * 8);
                acc[nt] = __builtin_amdgcn_mfma_f32_16x16x32_bf16(
                    afrag[ks], bf, acc[nt], 0, 0, 0);
            }
        }

        float vv[4][4];
        float ps[4] = {0.f, 0.f, 0.f, 0.f}, pd[4] = {0.f, 0.f, 0.f, 0.f};
#pragma unroll
        for (int nt = 0; nt < 4; ++nt) {
#pragma unroll
            for (int r = 0; r < 4; ++r) {
                const float v = acc[nt][r] * nm[r];
                vv[nt][r] = v;
                ps[r] += v * pa[nt];
                pd[r] += v * pb[nt];
            }
        }
#pragma unroll
        for (int r = 0; r < 4; ++r) {
            const int rr = r0 + kg * 4 + r;
            if (!rvld[r]) continue;
            ushort u0, u1, u2, u3;
            cvt2(vv[0][r], vv[1][r], u0, u1);
            cvt2(vv[2][r], vv[3][r], u2, u3);
            ushort* wrow = Wh_b + ((size_t)i * N_NODES + rr) * OUT_F + cl;
            wrow[0]  = u0;
            wrow[16] = u1;
            wrow[32] = u2;
            wrow[48] = u3;
        }
#pragma unroll
        for (int r = 0; r < 4; ++r) {
            float s1 = ps[r], s2 = pd[r];
#pragma unroll
            for (int off = 1; off < 16; off <<= 1) {
                s1 += __shfl_xor(s1, off, 64);
                s2 += __shfl_xor(s2, off, 64);
            }
            if (cl == 0 && rvld[r]) {
                const int rr = r0 + kg * 4 + r;
                p_src[i * N_NODES + rr] = s1;
                p_dst[i * N_NODES + rr] = s2;
            }
        }
    }
}

// ---------------------------------------------------------------------------
// Linked-list build (R11) + fused degree histogram.
// ---------------------------------------------------------------------------
__global__ __launch_bounds__(256) void build_kernel(
    const int* __restrict__ src, const int* __restrict__ dst,
    const float* __restrict__ p_src, const float* __restrict__ p_dst,
    int* __restrict__ head, int4* __restrict__ rec, int* __restrict__ deg)
{
    const int e = blockIdx.x * 256 + threadIdx.x;
    const int i = blockIdx.y;
    const int d = dst[(size_t)i * N_EDGE + e];
    const int s = src[(size_t)i * N_EDGE + e];
    float x = p_src[i * N_NODES + s] + p_dst[i * N_NODES + d];
    x = (x > 0.f) ? x : 0.2f * x;
    const float w = __expf(x);   // max-free softmax: logits O(4), no overflow
    union { float f; int i; } wb; wb.f = w;
    const int old = atomicExch(&head[i * N_NODES + d], e);
    atomicAdd(&deg[i * N_NODES + d], 1);
    rec[(size_t)i * EP1 + e] = make_int4(old, s << 7, wb.i, 0);
}

// ---------------------------------------------------------------------------
// Degree-balance, two-level counting sort (R15 lesson: NO hot global atomics).
// 1) bhist: per-block LDS histogram -> one global STORE per (block, bucket).
// ---------------------------------------------------------------------------
__global__ __launch_bounds__(256) void bhist_kernel(
    const int* __restrict__ deg, int* __restrict__ bhist)
{
    __shared__ int h[NBKT];
    const int t = threadIdx.x;
    if (t < NBKT) h[t] = 0;
    __syncthreads();
    const int n = blockIdx.x * 256 + t;
    const int i = blockIdx.y;
    if (n < N_NODES) {
        const int b = min(deg[i * N_NODES + n], NBKT - 1);
        atomicAdd(&h[b], 1);          // LDS atomic: cheap
    }
    __syncthreads();
    if (t < NBKT) bhist[((size_t)(i * NBKT + t)) * NBLK + blockIdx.x] = h[t];
}

// 2) bscan_blk: one block per (channel,bucket); exclusive-scan the 391 block
//    counts in place; emit bucket total.
__global__ __launch_bounds__(256) void bscan_blk_kernel(
    int* __restrict__ bhist, int* __restrict__ btot)
{
    __shared__ int lds[512];
    int* row = bhist + (size_t)blockIdx.x * NBLK;
    const int t = threadIdx.x;
    const int v0 = (t < NBLK) ? row[t] : 0;
    const int v1 = (256 + t < NBLK) ? row[256 + t] : 0;
    lds[t] = v0; lds[256 + t] = v1;
    __syncthreads();
    for (int off = 1; off < 512; off <<= 1) {
        int a = 0, b = 0;
        if (t >= off) a = lds[t - off];
        if (256 + t >= off) b = lds[256 + t - off];
        __syncthreads();
        if (t >= off) lds[t] += a;
        if (256 + t >= off) lds[256 + t] += b;
        __syncthreads();
    }
    if (t < NBLK) row[t] = lds[t] - v0;                  // exclusive
    if (256 + t < NBLK) row[256 + t] = lds[256 + t] - v1;
    if (t == 0) btot[blockIdx.x] = lds[511];
}

// 3) bktbase: scan the 256 bucket totals, segmented per channel.
__global__ __launch_bounds__(256) void bktbase_kernel(
    const int* __restrict__ btot, int* __restrict__ bktbase)
{
    __shared__ int lds[D_CH * NBKT];
    const int t = threadIdx.x;
    const int b = t & (NBKT - 1);
    const int i = t >> 6;
    const int c = btot[t];
    lds[t] = c;
    __syncthreads();
    for (int off = 1; off < NBKT; off <<= 1) {
        int v = 0;
        if (b >= off) v = lds[t - off];
        __syncthreads();
        if (b >= off) lds[t] += v;
        __syncthreads();
    }
    bktbase[t] = i * N_NODES + lds[t] - c;   // exclusive base within channel
}

// 4) perm: local rank via LDS cursor (returns old), pos = base+blockoff+rank.
//    Nondeterministic within-bucket order is fine: perm only assigns nodes to
//    wave slots; each node's output depends solely on its own chain.
__global__ __launch_bounds__(256) void perm_kernel(
    const int* __restrict__ deg, const int* __restrict__ bhist,
    const int* __restrict__ bktbase, int* __restrict__ perm)
{
    __shared__ int cur[NBKT];
    const int t = threadIdx.x;
    if (t < NBKT) cur[t] = 0;
    __syncthreads();
    const int n = blockIdx.x * 256 + t;
    const int i = blockIdx.y;
    if (n >= N_NODES) return;
    const int b = min(deg[i * N_NODES + n], NBKT - 1);
    const int lr = atomicAdd(&cur[b], 1);    // LDS atomic: cheap
    const int pos = bktbase[i * NBKT + b]
                  + bhist[((size_t)(i * NBKT + b)) * NBLK + blockIdx.x] + lr;
    perm[pos] = n;
}

// ---------------------------------------------------------------------------
// Aggregate via sentinel-terminated lists over DEGREE-BALANCED node groups.
// Termination sums PRE-ingest next pointers (R10 lesson).
// ---------------------------------------------------------------------------
__global__ __launch_bounds__(256) void agg_ll_kernel(
    const int* __restrict__ head, const int4* __restrict__ rec,
    const int* __restrict__ perm, const ushort* __restrict__ Wh_b,
    const float* __restrict__ norm, float* __restrict__ out)
{
    const int wv    = threadIdx.x >> 6;
    const int lane  = threadIdx.x & 63;
    const int lane2 = lane * 2;
    const int i     = blockIdx.y;
    const int n0    = (blockIdx.x * 4 + wv) * CPW;  // 8 perm slots

    const int4* __restrict__ recb = rec + (size_t)i * EP1;
    const char* __restrict__ whb0 =
        (const char*)(Wh_b + (size_t)i * N_NODES * OUT_F);

    int   nd[CPW], sb[CPW], en[CPW];
    float w[CPW], acc[CPW], z[CPW];
#pragma unroll
    for (int c = 0; c < CPW; ++c) {
        nd[c] = perm[i * N_NODES + n0 + c];
        const int4 r = recb[head[i * N_NODES + nd[c]]];
        sb[c]  = r.y;
        w[c]   = bits2f(r.z);
        en[c]  = r.x;
        acc[c] = 0.f;
        z[c]   = 0.f;
    }

    for (;;) {
        int sum = 0;
#pragma unroll
        for (int c = 0; c < CPW; ++c) {
            const float wh = bf2f(*(const ushort*)(whb0 + (sb[c] + lane2)));
            const int4  r  = recb[en[c]];

            acc[c] += w[c] * wh;     // w==0 on sentinel: harmless
            z[c]   += w[c];

            sum  += en[c];           // PRE-ingest: current's successor pointer

            sb[c] = r.y;
            w[c]  = bits2f(r.z);
            en[c] = r.x;
        }
        if (sum == CPW * N_EDGE) break;
    }

#pragma unroll
    for (int c = 0; c < CPW; ++c) {
        const int n = nd[c];
        float v = (z[c] > 0.f) ? (acc[c] / z[c]) * norm[n] : 0.f;
        out[(size_t)n * (D_CH * OUT_F) + i * OUT_F + lane] = (v > 0.f) ? v : 0.f;
    }
}

// ---------------------------------------------------------------------------
extern "C" void kernel_launch(void* const* d_in, const int* in_sizes, int n_in,
                              void* d_out, int out_size, void* d_ws, size_t ws_size,
                              hipStream_t stream)
{
    const float* feature = (const float*)d_in[0];
    const float* norm    = (const float*)d_in[1];
    const float* W       = (const float*)d_in[2];
    const float* att_w   = (const float*)d_in[3];
    const int*   src     = (const int*)d_in[4];
    const int*   dst     = (const int*)d_in[5];
    float* out = (float*)d_out;

    // Workspace (~111 MB): Wh_b | p_src | p_dst | head | rec | Bpack |
    // deg | perm | bhist[256*391] | btot[256] | bktbase[256]
    ushort* Wh_b  = (ushort*)d_ws;
    float*  p_src = (float*)(Wh_b + (size_t)M_SEG * OUT_F);
    float*  p_dst = p_src + M_SEG;
    int*    head  = (int*)(p_dst + M_SEG);
    int4*   rec   = (int4*)(head + M_SEG);
    ushort* Bpack = (ushort*)(rec + (size_t)D_CH * EP1);
    int*    deg   = (int*)(Bpack + 65536);
    int*    perm  = deg + M_SEG;
    int*    bhist = perm + M_SEG;
    int*    btot  = bhist + (size_t)D_CH * NBKT * NBLK;
    int*    bktbase = btot + D_CH * NBKT;

    bpack_kernel<<<dim3(32), 256, 0, stream>>>(W, Bpack);
    init_kernel<<<dim3((M_SEG + 255) / 256), 256, 0, stream>>>(head, rec, deg);
    gemm_mfma_kernel<<<dim3((N_NODES + GROWS - 1) / GROWS), 512, 0, stream>>>(
        feature, norm, Bpack, att_w, Wh_b, p_src, p_dst);
    build_kernel<<<dim3(N_EDGE / 256, D_CH), 256, 0, stream>>>(
        src, dst, p_src, p_dst, head, rec, deg);
    bhist_kernel<<<dim3(NBLK, D_CH), 256, 0, stream>>>(deg, bhist);
    bscan_blk_kernel<<<dim3(D_CH * NBKT), 256, 0, stream>>>(bhist, btot);
    bktbase_kernel<<<dim3(1), 256, 0, stream>>>(btot, bktbase);
    perm_kernel<<<dim3(NBLK, D_CH), 256, 0, stream>>>(deg, bhist, bktbase, perm);
    agg_ll_kernel<<<dim3(N_NODES / (4 * CPW), D_CH), 256, 0, stream>>>(
        head, rec, perm, Wh_b, norm, out);
}

// Round 17
// 386.609 us; speedup vs baseline: 4.1068x; 1.2329x over previous
//
#include <hip/hip_runtime.h>
#include <hip/hip_bf16.h>

#define N_NODES 100000
#define IN_F    256
#define OUT_F   64
#define D_CH    4
#define N_EDGE  800000
#define EP1     (N_EDGE + 1)               // per-channel rec slots (+1 sentinel)
#define M_SEG   (D_CH * N_NODES)          // 400000 segments
#define CPW     8                          // chains per wave (R7-proven optimum)
#define GROWS   128                        // gemm rows per block (8 waves)

typedef __attribute__((ext_vector_type(8))) short short8;
typedef __attribute__((ext_vector_type(4))) float f32x4;

__device__ inline ushort f2bf(float f) {           // round-to-nearest-even
    union { float f; unsigned u; } v; v.f = f;
    unsigned b = v.u + 0x7FFFu + ((v.u >> 16) & 1u);
    return (ushort)(b >> 16);
}
__device__ inline float bf2f(ushort u) {
    union { unsigned u; float f; } v; v.u = ((unsigned)u) << 16;
    return v.f;
}
__device__ inline float bits2f(int b) {
    union { int i; float f; } v; v.i = b; return v.f;
}
// native paired f32->bf16 (compiler emits v_cvt_pk_bf16_f32; RNE)
__device__ inline void cvt2(float a, float b, ushort& lo, ushort& hi) {
    __hip_bfloat162 h = __float22bfloat162_rn(float2{a, b});
    union { __hip_bfloat162 h; ushort2 u; } v; v.h = h;
    lo = v.u.x; hi = v.u.y;
}

// ---------------------------------------------------------------------------
// Setup (fused bpack + init): blocks cover 8192 bpack slots, then M_SEG
// head-sentinel inits + D_CH sentinel records.
// Bpack fragment (i, ks, nt): lane l, elem j holds
//   W[i][ks*32 + (l>>4)*8 + j][nt*16 + (l&15)]
// ---------------------------------------------------------------------------
__global__ __launch_bounds__(256) void setup_kernel(
    const float* __restrict__ W, ushort* __restrict__ Bpack,
    int* __restrict__ head, int4* __restrict__ rec)
{
    const int t = blockIdx.x * 256 + threadIdx.x;
    if (t < D_CH * 8 * 4 * 64) {                       // 8192 bpack slots
        const int l  = t & 63;
        const int nt = (t >> 6) & 3;
        const int ks = (t >> 8) & 7;
        const int i  = t >> 11;
        const int n  = nt * 16 + (l & 15);
        const int k0 = ks * 32 + (l >> 4) * 8;
        ushort v[8];
#pragma unroll
        for (int j = 0; j < 8; ++j)
            v[j] = f2bf(W[((size_t)i * IN_F + k0 + j) * OUT_F + n]);
#pragma unroll
        for (int j = 0; j < 8; ++j)
            Bpack[(size_t)t * 8 + j] = v[j];
    }
    const int u = t - 8192;
    if (u >= 0 && u < M_SEG) head[u] = N_EDGE;
    if (u >= 0 && u < D_CH)
        rec[(size_t)u * EP1 + N_EDGE] = make_int4(N_EDGE, 0, 0, 0);
}

// ---------------------------------------------------------------------------
// MFMA GEMM + fused pvec epilogue. 8 waves/128 rows; B staged in LDS. (R13)
// C/D layout (HW-verified): col = lane&15, row = (lane>>4)*4 + reg.
// ---------------------------------------------------------------------------
__global__ __launch_bounds__(512) void gemm_mfma_kernel(
    const float* __restrict__ feature, const float* __restrict__ norm,
    const ushort* __restrict__ Bpack, const float* __restrict__ att_w,
    ushort* __restrict__ Wh_b, float* __restrict__ p_src, float* __restrict__ p_dst)
{
    __shared__ ushort Blds[16384];            // 32KB: one channel's 32 fragments
    const int wv   = threadIdx.x >> 6;        // 0..7
    const int lane = threadIdx.x & 63;
    const int kg   = lane >> 4;
    const int cl   = lane & 15;
    const int r0   = blockIdx.x * GROWS + wv * 16;

    const int rowm   = r0 + cl;
    const int rclamp = (rowm < N_NODES) ? rowm : (N_NODES - 1);
    const float* __restrict__ arow = feature + (size_t)rclamp * IN_F + kg * 8;
    short8 afrag[8];
#pragma unroll
    for (int ks = 0; ks < 8; ++ks) {
        const f32x4 x = *(const f32x4*)(arow + ks * 32);
        const f32x4 y = *(const f32x4*)(arow + ks * 32 + 4);
        ushort u[8];
        cvt2(x[0], x[1], u[0], u[1]);
        cvt2(x[2], x[3], u[2], u[3]);
        cvt2(y[0], y[1], u[4], u[5]);
        cvt2(y[2], y[3], u[6], u[7]);
        short8 a;
#pragma unroll
        for (int j = 0; j < 8; ++j) a[j] = (short)u[j];
        afrag[ks] = a;
    }

    float pa[4], pb[4];
#pragma unroll
    for (int nt = 0; nt < 4; ++nt) {
        pa[nt] = att_w[nt * 16 + cl];
        pb[nt] = att_w[OUT_F + nt * 16 + cl];
    }
    float nm[4];
    bool  rvld[4];
#pragma unroll
    for (int r = 0; r < 4; ++r) {
        const int rr = r0 + kg * 4 + r;
        rvld[r] = rr < N_NODES;
        nm[r] = rvld[r] ? norm[rr] : 0.f;
    }

    for (int i = 0; i < D_CH; ++i) {
        __syncthreads();
        {
            const uint4* __restrict__ s4 = (const uint4*)(Bpack + (size_t)i * 16384);
            uint4* d4 = (uint4*)Blds;
#pragma unroll
            for (int t = 0; t < 4; ++t)
                d4[threadIdx.x + t * 512] = s4[threadIdx.x + t * 512];
        }
        __syncthreads();

        f32x4 acc[4];
#pragma unroll
        for (int nt = 0; nt < 4; ++nt) acc[nt] = (f32x4){0.f, 0.f, 0.f, 0.f};

#pragma unroll
        for (int ks = 0; ks < 8; ++ks) {
#pragma unroll
            for (int nt = 0; nt < 4; ++nt) {
                const short8 bf =
                    *(const short8*)(Blds + (((ks * 4 + nt) << 6) + lane) * 8);
                acc[nt] = __builtin_amdgcn_mfma_f32_16x16x32_bf16(
                    afrag[ks], bf, acc[nt], 0, 0, 0);
            }
        }

        float vv[4][4];
        float ps[4] = {0.f, 0.f, 0.f, 0.f}, pd[4] = {0.f, 0.f, 0.f, 0.f};
#pragma unroll
        for (int nt = 0; nt < 4; ++nt) {
#pragma unroll
            for (int r = 0; r < 4; ++r) {
                const float v = acc[nt][r] * nm[r];
                vv[nt][r] = v;
                ps[r] += v * pa[nt];
                pd[r] += v * pb[nt];
            }
        }
#pragma unroll
        for (int r = 0; r < 4; ++r) {
            const int rr = r0 + kg * 4 + r;
            if (!rvld[r]) continue;
            ushort u0, u1, u2, u3;
            cvt2(vv[0][r], vv[1][r], u0, u1);
            cvt2(vv[2][r], vv[3][r], u2, u3);
            ushort* wrow = Wh_b + ((size_t)i * N_NODES + rr) * OUT_F + cl;
            wrow[0]  = u0;
            wrow[16] = u1;
            wrow[32] = u2;
            wrow[48] = u3;
        }
#pragma unroll
        for (int r = 0; r < 4; ++r) {
            float s1 = ps[r], s2 = pd[r];
#pragma unroll
            for (int off = 1; off < 16; off <<= 1) {
                s1 += __shfl_xor(s1, off, 64);
                s2 += __shfl_xor(s2, off, 64);
            }
            if (cl == 0 && rvld[r]) {
                const int rr = r0 + kg * 4 + r;
                p_src[i * N_NODES + rr] = s1;
                p_dst[i * N_NODES + rr] = s2;
            }
        }
    }
}

// ---------------------------------------------------------------------------
// Linked-list build (R11-proven, NO deg — the deg pass cost 130µs > the 60µs
// balance saving, R16 ledger): rec[i][e] = {next, s<<7, w_bits, 0}.
// rec writes SEQUENTIAL 16B; head (1.6MB, L2) random atomicExch.
// ---------------------------------------------------------------------------
__global__ __launch_bounds__(256) void build_kernel(
    const int* __restrict__ src, const int* __restrict__ dst,
    const float* __restrict__ p_src, const float* __restrict__ p_dst,
    int* __restrict__ head, int4* __restrict__ rec)
{
    const int e = blockIdx.x * 256 + threadIdx.x;
    const int i = blockIdx.y;
    const int d = dst[(size_t)i * N_EDGE + e];
    const int s = src[(size_t)i * N_EDGE + e];
    float x = p_src[i * N_NODES + s] + p_dst[i * N_NODES + d];
    x = (x > 0.f) ? x : 0.2f * x;
    const float w = __expf(x);   // max-free softmax: logits O(4), no overflow
    union { float f; int i; } wb; wb.f = w;
    const int old = atomicExch(&head[i * N_NODES + d], e);
    rec[(size_t)i * EP1 + e] = make_int4(old, s << 7, wb.i, 0);
}

// ---------------------------------------------------------------------------
// Aggregate via sentinel-terminated lists (R11-proven): CPW=8 chains/wave,
// channel in blockIdx.y, zero selects in the inner loop; termination sums
// PRE-ingest next pointers (R10 lesson). Per edge: 1 broadcast rec line +
// 1 coalesced 128B Wh row; single wait point per iteration.
// ---------------------------------------------------------------------------
__global__ __launch_bounds__(256) void agg_ll_kernel(
    const int* __restrict__ head, const int4* __restrict__ rec,
    const ushort* __restrict__ Wh_b, const float* __restrict__ norm,
    float* __restrict__ out)
{
    const int wv    = threadIdx.x >> 6;
    const int lane  = threadIdx.x & 63;
    const int lane2 = lane * 2;
    const int i     = blockIdx.y;
    const int n0    = (blockIdx.x * 4 + wv) * CPW;  // 8 consecutive nodes

    const int4* __restrict__ recb = rec + (size_t)i * EP1;
    const char* __restrict__ whb0 =
        (const char*)(Wh_b + (size_t)i * N_NODES * OUT_F);

    // ---- prologue: ingest head edge of each chain ----
    int   sb[CPW], en[CPW];
    float w[CPW], acc[CPW], z[CPW];
#pragma unroll
    for (int c = 0; c < CPW; ++c) {
        const int4 r = recb[head[i * N_NODES + n0 + c]];
        sb[c]  = r.y;
        w[c]   = bits2f(r.z);
        en[c]  = r.x;
        acc[c] = 0.f;
        z[c]   = 0.f;
    }

    for (;;) {
        int sum = 0;
#pragma unroll
        for (int c = 0; c < CPW; ++c) {
            // two independent loads -> single wait covers both
            const float wh = bf2f(*(const ushort*)(whb0 + (sb[c] + lane2)));
            const int4  r  = recb[en[c]];

            acc[c] += w[c] * wh;     // w==0 on sentinel: harmless
            z[c]   += w[c];

            sum  += en[c];           // PRE-ingest: current's successor pointer

            sb[c] = r.y;
            w[c]  = bits2f(r.z);
            en[c] = r.x;
        }
        if (sum == CPW * N_EDGE) break;
    }

#pragma unroll
    for (int c = 0; c < CPW; ++c) {
        const int n = n0 + c;
        float v = (z[c] > 0.f) ? (acc[c] / z[c]) * norm[n] : 0.f;
        out[(size_t)n * (D_CH * OUT_F) + i * OUT_F + lane] = (v > 0.f) ? v : 0.f;
    }
}

// ---------------------------------------------------------------------------
extern "C" void kernel_launch(void* const* d_in, const int* in_sizes, int n_in,
                              void* d_out, int out_size, void* d_ws, size_t ws_size,
                              hipStream_t stream)
{
    const float* feature = (const float*)d_in[0];
    const float* norm    = (const float*)d_in[1];
    const float* W       = (const float*)d_in[2];
    const float* att_w   = (const float*)d_in[3];
    const int*   src     = (const int*)d_in[4];
    const int*   dst     = (const int*)d_in[5];
    float* out = (float*)d_out;

    // Workspace layout (~108 MB):
    // Wh_b[25.6M u16 = 51.2MB] | p_src[400K f] | p_dst[400K f] |
    // head[400K i] | rec[4*(E+1) int4 = 51.2MB] | Bpack[65536 u16]
    ushort* Wh_b  = (ushort*)d_ws;
    float*  p_src = (float*)(Wh_b + (size_t)M_SEG * OUT_F);
    float*  p_dst = p_src + M_SEG;
    int*    head  = (int*)(p_dst + M_SEG);
    int4*   rec   = (int4*)(head + M_SEG);
    ushort* Bpack = (ushort*)(rec + (size_t)D_CH * EP1);

    setup_kernel<<<dim3((8192 + M_SEG + 255) / 256), 256, 0, stream>>>(
        W, Bpack, head, rec);
    gemm_mfma_kernel<<<dim3((N_NODES + GROWS - 1) / GROWS), 512, 0, stream>>>(
        feature, norm, Bpack, att_w, Wh_b, p_src, p_dst);
    build_kernel<<<dim3(N_EDGE / 256, D_CH), 256, 0, stream>>>(
        src, dst, p_src, p_dst, head, rec);
    agg_ll_kernel<<<dim3(N_NODES / (4 * CPW), D_CH), 256, 0, stream>>>(
        head, rec, Wh_b, norm, out);
}